// Round 1
// baseline (2219.955 us; speedup 1.0000x reference)
//
#include <hip/hip_runtime.h>
#include <math.h>

// Problem constants
#define B 8
#define IC 256
#define OC 256
#define SDIM 512
#define H 128
#define W 128
#define OH 64
#define OW 64
#define EPS 1e-8f
#define SQRT2 1.41421356237309504880f
#define SCALE 0.02083333395421505f   // 1/sqrt(256*9) as float

// Workspace layout (floats):
//  xblur  : B*IC*H*W   = 33554432
//  style  : B*IC       = 2048
//  wsq    : OC*IC      = 65536
//  demod  : B*OC       = 2048
//  ssq    : B*IC       = 2048
//  factor : B*IC       = 2048
// total ~128.3 MB

// ---------------- style = s @ style_w^T + style_b  [B, IC] ----------------
__global__ void style_kernel(const float* __restrict__ s,
                             const float* __restrict__ sw,
                             const float* __restrict__ sb,
                             float* __restrict__ style) {
    int i = blockIdx.x * 256 + threadIdx.x;   // 0..2047
    int b = i >> 8, ic = i & 255;
    const float* sv = s + (size_t)b * SDIM;
    const float* wv = sw + (size_t)ic * SDIM;
    float sum = 0.f;
    for (int k = 0; k < SDIM; ++k) sum = fmaf(sv[k], wv[k], sum);
    style[i] = sum + sb[ic];
}

// ---------------- wsq[o,i] = sum_tap w^2 ----------------
__global__ void wsq_kernel(const float* __restrict__ w, float* __restrict__ wsq) {
    int i = blockIdx.x * 256 + threadIdx.x;   // 0..65535
    const float* p = w + (size_t)i * 9;
    float sum = 0.f;
    for (int k = 0; k < 9; ++k) sum = fmaf(p[k], p[k], sum);
    wsq[i] = sum;
}

// ---------------- demod[b,o] = rsqrt(scale^2 * sum_i style^2*wsq + eps); also zero ssq --------
__global__ void demod_kernel(const float* __restrict__ style,
                             const float* __restrict__ wsq,
                             float* __restrict__ demod,
                             float* __restrict__ ssq) {
    int i = blockIdx.x * 256 + threadIdx.x;   // 0..2047  (b*256+o)
    int b = i >> 8, o = i & 255;
    const float* st = style + b * 256;
    const float* wq = wsq + (size_t)o * 256;
    float sum = 0.f;
    for (int ic = 0; ic < 256; ++ic) {
        float sv = st[ic];
        sum = fmaf(sv * sv, wq[ic], sum);
    }
    demod[i] = rsqrtf(SCALE * SCALE * sum + EPS);
    ssq[i] = 0.f;   // zero accumulator for blur's atomic sum-of-squares
}

// ---------------- separable 5x5 binomial blur, strip of 32 rows per block --------------
// writes blurred x (unnormalized) + atomicAdd per-(b,c) sum of squares
__global__ __launch_bounds__(256) void blur_kernel(const float* __restrict__ x,
                                                   float* __restrict__ xblur,
                                                   float* __restrict__ ssq) {
    __shared__ float img[36][128];
    __shared__ float tmp[36][128];
    __shared__ float red[4];
    int t = threadIdx.x;
    int strip = blockIdx.x & 3;       // 4 strips of 32 rows
    int bc = blockIdx.x >> 2;         // 0..2047 (b*256+c)
    int r0 = strip * 32;
    const size_t base = (size_t)bc * (H * W);

    // load rows r0-2 .. r0+33 (zero outside)
    #pragma unroll
    for (int k = 0; k < 18; ++k) {
        int e = t + k * 256;          // 0..4607
        int lr = e >> 7, c = e & 127;
        int gr = r0 - 2 + lr;
        img[lr][c] = (gr >= 0 && gr < H) ? x[base + (size_t)gr * W + c] : 0.f;
    }
    __syncthreads();
    // horizontal pass (1 4 6 4 1)
    #pragma unroll
    for (int k = 0; k < 18; ++k) {
        int e = t + k * 256;
        int lr = e >> 7, c = e & 127;
        float sum = 6.f * img[lr][c];
        sum += 4.f * ((c >= 1 ? img[lr][c - 1] : 0.f) + (c <= 126 ? img[lr][c + 1] : 0.f));
        sum += (c >= 2 ? img[lr][c - 2] : 0.f) + (c <= 125 ? img[lr][c + 2] : 0.f);
        tmp[lr][c] = sum;
    }
    __syncthreads();
    // vertical pass + sum of squares
    float ss = 0.f;
    #pragma unroll
    for (int k = 0; k < 16; ++k) {
        int e = t + k * 256;          // 0..4095
        int lr = (e >> 7) + 2, c = e & 127;   // lr 2..33
        float sum = 6.f * tmp[lr][c] + 4.f * (tmp[lr - 1][c] + tmp[lr + 1][c])
                  + (tmp[lr - 2][c] + tmp[lr + 2][c]);
        sum *= (1.0f / 256.0f);
        ss = fmaf(sum, sum, ss);
        xblur[base + (size_t)(r0 + (e >> 7)) * W + c] = sum;
    }
    // block reduce ss, one atomic per block
    for (int off = 32; off; off >>= 1) ss += __shfl_down(ss, off, 64);
    if ((t & 63) == 0) red[t >> 6] = ss;
    __syncthreads();
    if (t == 0) atomicAdd(&ssq[bc], red[0] + red[1] + red[2] + red[3]);
}

// ---------------- factor[b,c] = rsqrt(ms+eps) * g[c] * style[b,c] * scale --------------
__global__ void factor_kernel(const float* __restrict__ ssq,
                              const float* __restrict__ style,
                              const float* __restrict__ g,
                              float* __restrict__ factor) {
    int i = blockIdx.x * 256 + threadIdx.x;   // 0..2047
    int c = i & 255;
    float ms = ssq[i] * (1.0f / (H * W));
    factor[i] = rsqrtf(ms + EPS) * g[c] * style[i] * SCALE;
}

// ---------------- direct conv 3x3 stride2 pad1, demod+bias+lrelu epilogue --------------
// Block: 256 threads -> tile 64 oc x 64 ow at one (b, h0). Thread: 4 oc x 4 ow.
// LDS: x chunk [16 ic][3 rows][130 cols(+pads)] + w chunk [64 oc][145 (16ic*9+pad)]
__global__ __launch_bounds__(256) void conv_kernel(const float* __restrict__ xblur,
                                                   const float* __restrict__ wgt,
                                                   const float* __restrict__ demod,
                                                   const float* __restrict__ bias,
                                                   const float* __restrict__ factor,
                                                   float* __restrict__ out) {
    __shared__ float xt[16 * 3 * 130];   // [ic][tau][col] col = iw+1
    __shared__ float wt[64 * 145];       // [ol][ic*9+tap], stride 145 breaks bank conflict

    const int t = threadIdx.x;
    const int h0 = blockIdx.x;           // 0..63
    const int og0 = blockIdx.y * 64;     // output-channel tile base
    const int b = blockIdx.z;
    const int wg = t & 15;               // 16 w-groups
    const int og = t >> 4;               // 16 o-groups
    const int w0 = wg * 4;
    const int ol0 = og * 4;

    float acc[4][4] = {};

    // zero left/right pads once (never overwritten)
    if (t < 48) {
        int ic = t / 3, tau = t % 3;
        xt[(ic * 3 + tau) * 130 + 0] = 0.f;
        xt[(ic * 3 + tau) * 130 + 129] = 0.f;
    }

    for (int chunk = 0; chunk < 16; ++chunk) {
        int ic0 = chunk * 16;
        __syncthreads();
        // stage x: 16 ic * 3 rows * 128 cols, with per-channel modulation factor folded in
        #pragma unroll
        for (int k = 0; k < 24; ++k) {
            int e = t + k * 256;                 // 0..6143
            int ic = e / 384;
            int rem = e - ic * 384;
            int tau = rem >> 7;
            int col = rem & 127;
            int ih = 2 * h0 - 1 + tau;
            float v = 0.f;
            if (ih >= 0)
                v = xblur[(((size_t)b * IC + ic0 + ic) * H + ih) * W + col]
                    * factor[b * IC + ic0 + ic];
            xt[(ic * 3 + tau) * 130 + col + 1] = v;
        }
        // stage w: 64 oc * 16 ic * 9 taps
        #pragma unroll
        for (int k = 0; k < 36; ++k) {
            int e = t + k * 256;                 // 0..9215
            int ol = e / 144;
            int rem = e - ol * 144;              // ic*9+tap
            wt[ol * 145 + rem] = wgt[((size_t)(og0 + ol) * IC + ic0) * 9 + rem];
        }
        __syncthreads();
        // compute
        #pragma unroll
        for (int ic = 0; ic < 16; ++ic) {
            float xv[3][9];
            #pragma unroll
            for (int ta = 0; ta < 3; ++ta)
                #pragma unroll
                for (int cc = 0; cc < 9; ++cc)
                    xv[ta][cc] = xt[(ic * 3 + ta) * 130 + 2 * w0 + cc];
            #pragma unroll
            for (int j = 0; j < 4; ++j) {
                float wv[9];
                #pragma unroll
                for (int q = 0; q < 9; ++q) wv[q] = wt[(ol0 + j) * 145 + ic * 9 + q];
                #pragma unroll
                for (int ww = 0; ww < 4; ++ww)
                    #pragma unroll
                    for (int th = 0; th < 3; ++th)
                        #pragma unroll
                        for (int tw = 0; tw < 3; ++tw)
                            acc[j][ww] = fmaf(wv[th * 3 + tw], xv[th][2 * ww + tw], acc[j][ww]);
            }
        }
    }

    // epilogue: demod, bias, scaled LeakyReLU, vectorized store
    #pragma unroll
    for (int j = 0; j < 4; ++j) {
        int o = og0 + ol0 + j;
        float dd = demod[b * OC + o];
        float bb = bias[o];
        float4 r;
        float* pr = &r.x;
        #pragma unroll
        for (int ww = 0; ww < 4; ++ww) {
            float v = fmaf(acc[j][ww], dd, bb);
            v = (v >= 0.f ? v : 0.2f * v) * SQRT2;
            pr[ww] = v;
        }
        size_t oidx = (((size_t)b * OC + o) * OH + h0) * OW + w0;
        *(float4*)(out + oidx) = r;
    }
}

extern "C" void kernel_launch(void* const* d_in, const int* in_sizes, int n_in,
                              void* d_out, int out_size, void* d_ws, size_t ws_size,
                              hipStream_t stream) {
    const float* x   = (const float*)d_in[0];
    const float* s   = (const float*)d_in[1];
    const float* cw  = (const float*)d_in[2];
    const float* cb  = (const float*)d_in[3];
    const float* sw  = (const float*)d_in[4];
    const float* sb  = (const float*)d_in[5];
    const float* ng  = (const float*)d_in[6];
    float* out = (float*)d_out;

    float* ws = (float*)d_ws;
    float* xblur  = ws;                      // 33554432
    float* style  = xblur + (size_t)B * IC * H * W;
    float* wsq    = style + B * IC;          // 65536
    float* demod  = wsq + OC * IC;           // 2048
    float* ssq    = demod + B * OC;          // 2048
    float* factor = ssq + B * IC;            // 2048

    style_kernel<<<8, 256, 0, stream>>>(s, sw, sb, style);
    wsq_kernel<<<256, 256, 0, stream>>>(cw, wsq);
    demod_kernel<<<8, 256, 0, stream>>>(style, wsq, demod, ssq);
    blur_kernel<<<B * IC * 4, 256, 0, stream>>>(x, xblur, ssq);
    factor_kernel<<<8, 256, 0, stream>>>(ssq, style, ng, factor);
    conv_kernel<<<dim3(OH, OC / 64, B), 256, 0, stream>>>(xblur, cw, demod, cb, factor, out);
}

// Round 2
// 356.380 us; speedup vs baseline: 6.2292x; 6.2292x over previous
//
#include <hip/hip_runtime.h>
#include <hip/hip_bf16.h>
#include <math.h>

#define B 8
#define IC 256
#define OC 256
#define SDIM 512
#define H 128
#define W 128
#define OH 64
#define OW 64
#define EPS 1e-8f
#define SQRT2 1.41421356237309504880f
#define SCALE 0.02083333395421505f   // 1/sqrt(256*9)

#define RS 16640        // xbp row stride in elems (65*256)
#define PLANE 1081600   // 65*65*256 elems per phase plane

typedef unsigned short u16;
typedef unsigned int u32;
typedef __attribute__((ext_vector_type(8))) short s16x8;
typedef __attribute__((ext_vector_type(4))) float f32x4;

// ---------------- style = s @ style_w^T + style_b  [B, IC] ----------------
__global__ void style_kernel(const float* __restrict__ s,
                             const float* __restrict__ sw,
                             const float* __restrict__ sb,
                             float* __restrict__ style) {
    int i = blockIdx.x * 256 + threadIdx.x;
    int b = i >> 8, ic = i & 255;
    const float* sv = s + (size_t)b * SDIM;
    const float* wv = sw + (size_t)ic * SDIM;
    float sum = 0.f;
    for (int k = 0; k < SDIM; ++k) sum = fmaf(sv[k], wv[k], sum);
    style[i] = sum + sb[ic];
}

// ---------------- wsq[o,i] = sum_tap w^2 ----------------
__global__ void wsq_kernel(const float* __restrict__ w, float* __restrict__ wsq) {
    int i = blockIdx.x * 256 + threadIdx.x;
    const float* p = w + (size_t)i * 9;
    float sum = 0.f;
    for (int k = 0; k < 9; ++k) sum = fmaf(p[k], p[k], sum);
    wsq[i] = sum;
}

// ---------------- demod[b,o] = rsqrt(scale^2 * sum_i style^2*wsq + eps); zero ssq --------
__global__ void demod_kernel(const float* __restrict__ style,
                             const float* __restrict__ wsq,
                             float* __restrict__ demod,
                             float* __restrict__ ssq) {
    int i = blockIdx.x * 256 + threadIdx.x;   // b*256+o
    int b = i >> 8, o = i & 255;
    const float* st = style + b * 256;
    const float* wq = wsq + (size_t)o * 256;
    float sum = 0.f;
    for (int ic = 0; ic < 256; ++ic) {
        float sv = st[ic];
        sum = fmaf(sv * sv, wq[ic], sum);
    }
    demod[i] = rsqrtf(SCALE * SCALE * sum + EPS);
    ssq[i] = 0.f;
}

// ---------------- separable 5x5 binomial blur -> bf16 xblur + ssq atomics --------------
__global__ __launch_bounds__(256) void blur_kernel(const float* __restrict__ x,
                                                   __hip_bfloat16* __restrict__ xblur,
                                                   float* __restrict__ ssq) {
    __shared__ float img[36][128];
    __shared__ float tmp[36][128];
    __shared__ float red[4];
    int t = threadIdx.x;
    int strip = blockIdx.x & 3;
    int bc = blockIdx.x >> 2;         // b*256+c
    int r0 = strip * 32;
    const size_t base = (size_t)bc * (H * W);

    #pragma unroll
    for (int k = 0; k < 18; ++k) {
        int e = t + k * 256;
        int lr = e >> 7, c = e & 127;
        int gr = r0 - 2 + lr;
        img[lr][c] = (gr >= 0 && gr < H) ? x[base + (size_t)gr * W + c] : 0.f;
    }
    __syncthreads();
    #pragma unroll
    for (int k = 0; k < 18; ++k) {
        int e = t + k * 256;
        int lr = e >> 7, c = e & 127;
        float sum = 6.f * img[lr][c];
        sum += 4.f * ((c >= 1 ? img[lr][c - 1] : 0.f) + (c <= 126 ? img[lr][c + 1] : 0.f));
        sum += (c >= 2 ? img[lr][c - 2] : 0.f) + (c <= 125 ? img[lr][c + 2] : 0.f);
        tmp[lr][c] = sum;
    }
    __syncthreads();
    float ss = 0.f;
    #pragma unroll
    for (int k = 0; k < 16; ++k) {
        int e = t + k * 256;
        int lr = (e >> 7) + 2, c = e & 127;
        float sum = 6.f * tmp[lr][c] + 4.f * (tmp[lr - 1][c] + tmp[lr + 1][c])
                  + (tmp[lr - 2][c] + tmp[lr + 2][c]);
        sum *= (1.0f / 256.0f);
        ss = fmaf(sum, sum, ss);
        xblur[base + (size_t)(r0 + (e >> 7)) * W + c] = __float2bfloat16(sum);
    }
    for (int off = 32; off; off >>= 1) ss += __shfl_down(ss, off, 64);
    if ((t & 63) == 0) red[t >> 6] = ss;
    __syncthreads();
    if (t == 0) atomicAdd(&ssq[bc], red[0] + red[1] + red[2] + red[3]);
}

// ---------------- factor[b,c] = rsqrt(ms+eps) * g[c] * style[b,c] * scale --------------
__global__ void factor_kernel(const float* __restrict__ ssq,
                              const float* __restrict__ style,
                              const float* __restrict__ g,
                              float* __restrict__ factor) {
    int i = blockIdx.x * 256 + threadIdx.x;
    int c = i & 255;
    float ms = ssq[i] * (1.0f / (H * W));
    factor[i] = rsqrtf(ms + EPS) * g[c] * style[i] * SCALE;
}

// ---------------- wf[b][o][t*256+ic] = w[o][ic][t] * demod[b,o] * factor[b,ic] (bf16) ----
__global__ void wf_kernel(const float* __restrict__ w,
                          const float* __restrict__ demod,
                          const float* __restrict__ factor,
                          __hip_bfloat16* __restrict__ wf) {
    int bo = blockIdx.x;               // b*256+o
    int b = bo >> 8, o = bo & 255;
    int ic = threadIdx.x;
    float m = demod[bo] * factor[(b << 8) + ic];
    const float* wp = w + ((size_t)o * 256 + ic) * 9;
    __hip_bfloat16* dst = wf + (size_t)bo * 2304 + ic;
    #pragma unroll
    for (int t = 0; t < 9; ++t)
        dst[t * 256] = __float2bfloat16(wp[t] * m);
}

// ---------------- zero the pad row 0 / col 0 of each phase plane ----------------
__global__ void zeropad_kernel(__hip_bfloat16* __restrict__ xbp) {
    int p = blockIdx.x;               // 0..31 (b*4+phase)
    int t = threadIdx.x;
    char* base = (char*)(xbp + (size_t)p * PLANE);
    uint4 z = {0u, 0u, 0u, 0u};
    // row 0: 16640 elems = 2080 chunks of 8
    for (int k = 0; k < 9; ++k) {
        int c = t + (k << 8);
        if (c < 2080) *(uint4*)(base + (size_t)c * 16) = z;
    }
    // col 0: rows 1..64, 256 elems each = 2048 chunks
    for (int k = 0; k < 8; ++k) {
        int c = t + (k << 8);
        int r = 1 + (c >> 5);
        int off = (c & 31) << 3;
        *(uint4*)(base + ((size_t)r * RS + off) * 2) = z;
    }
}

// ---------------- pack: bf16 NCHW -> channel-last padded phase planes ----------------
// block: 64 ic x 64 w at one (b, h); transpose through LDS
__global__ __launch_bounds__(256) void pack_kernel(const __hip_bfloat16* __restrict__ xblur,
                                                   __hip_bfloat16* __restrict__ xbp) {
    __shared__ u16 tile[64][66];      // row stride 132 B -> 2-way max on both phases
    int t = threadIdx.x;
    int w0 = blockIdx.x << 6;
    int ic0 = blockIdx.y << 6;
    int z = blockIdx.z;
    int b = z >> 7, h = z & 127;
    int ph = h & 1, r = h >> 1;

    #pragma unroll
    for (int k = 0; k < 2; ++k) {
        int c = t + (k << 8);
        int ic_l = c >> 3, wc = c & 7;
        uint4 v = *(const uint4*)(xblur + (((size_t)(b * 256 + ic0 + ic_l)) << 14)
                                  + (h << 7) + w0 + (wc << 3));
        u32* dst = (u32*)&tile[ic_l][wc << 3];
        const u32* sv = (const u32*)&v;
        dst[0] = sv[0]; dst[1] = sv[1]; dst[2] = sv[2]; dst[3] = sv[3];
    }
    __syncthreads();
    #pragma unroll
    for (int k = 0; k < 2; ++k) {
        int c = t + (k << 8);
        int w_l = c >> 3, icg = c & 7;
        int w = w0 + w_l;
        int pw = w & 1, col = w >> 1;
        u32 pk[4];
        #pragma unroll
        for (int q = 0; q < 4; ++q) {
            u32 lo = tile[(icg << 3) + 2 * q][w_l];
            u32 hi = tile[(icg << 3) + 2 * q + 1][w_l];
            pk[q] = lo | (hi << 16);
        }
        size_t off = (size_t)((b << 2) + (ph << 1) + pw) * PLANE
                   + (size_t)(r + 1) * RS + (size_t)(col + 1) * 256 + ic0 + (icg << 3);
        *(uint4*)(xbp + off) = *(const uint4*)pk;
    }
}

// ---------------- MFMA implicit-GEMM conv ----------------
__device__ __forceinline__ void gl_lds16(const void* g, void* l) {
    __builtin_amdgcn_global_load_lds((const __attribute__((address_space(1))) u32*)g,
                                     (__attribute__((address_space(3))) u32*)l, 16, 0, 0);
}

__global__ __launch_bounds__(256, 2) void conv_kernel(const __hip_bfloat16* __restrict__ xbp,
                                                      const __hip_bfloat16* __restrict__ wf,
                                                      const float* __restrict__ bias,
                                                      float* __restrict__ out) {
    __shared__ char lds[16384];       // A: [0,8192) 128 rows x 64B ; B: [8192,16384)
    const int t = threadIdx.x;
    const int o0 = blockIdx.x << 7;
    const int n0 = blockIdx.y << 7;
    const int b  = blockIdx.z;
    const size_t bb = (size_t)b << 8;

    // staging: granule g = t (rows 0..63) and g = t+256 (rows 64..127)
    const int mA  = t >> 2;           // row within half-tile
    const int kgl = t & 3;
    const int kga = kgl ^ ((mA >> 1) & 3);    // XOR swizzle (same for +64 rows)
    size_t preA0 = (bb + o0 + mA) * 2304 + (kga << 3);
    size_t preA1 = preA0 + (size_t)64 * 2304;
    const int ow = mA & 63;
    size_t preB0 = (size_t)(blockIdx.y << 1) * RS + (size_t)ow * 256 + (kga << 3);
    size_t preB1 = preB0 + RS;        // oh+1
    char* dA0 = lds + t * 16;
    char* dA1 = lds + 4096 + t * 16;
    char* dB0 = lds + 8192 + t * 16;
    char* dB1 = lds + 12288 + t * 16;

    // fragment read addressing
    const int lane = t & 63, wave = t >> 6;
    const int lr = lane & 15, quad = lane >> 4;
    const int mb = (wave & 1) << 6;
    const int nb = (wave >> 1) << 6;
    const int fragoff = ((quad ^ ((lr >> 1) & 3)) << 4);

    f32x4 acc[4][4];
    #pragma unroll
    for (int i = 0; i < 4; ++i)
        #pragma unroll
        for (int j = 0; j < 4; ++j) acc[i][j] = (f32x4){0.f, 0.f, 0.f, 0.f};

    for (int kk = 0; kk < 72; ++kk) {
        int tap = kk >> 3;
        int ic0 = (kk & 7) << 5;
        int th = (tap * 11) >> 5;                 // tap/3
        int tw = tap - th * 3;
        int ph  = (th == 1) ? 0 : 1;
        int dhp = (th == 0) ? 0 : 1;
        int pw  = (tw == 1) ? 0 : 1;
        int dwp = (tw == 0) ? 0 : 1;
        size_t boff = (size_t)((b << 2) + (ph << 1) + pw) * PLANE
                    + (size_t)dhp * RS + (dwp << 8) + ic0;
        size_t aoff = (size_t)kk << 5;

        __syncthreads();
        gl_lds16(wf + preA0 + aoff, dA0);
        gl_lds16(wf + preA1 + aoff, dA1);
        gl_lds16(xbp + preB0 + boff, dB0);
        gl_lds16(xbp + preB1 + boff, dB1);
        __syncthreads();

        s16x8 a[4], bf[4];
        #pragma unroll
        for (int i = 0; i < 4; ++i)
            a[i] = *(const s16x8*)(lds + ((mb + (i << 4) + lr) << 6) + fragoff);
        #pragma unroll
        for (int j = 0; j < 4; ++j)
            bf[j] = *(const s16x8*)(lds + 8192 + ((nb + (j << 4) + lr) << 6) + fragoff);
        #pragma unroll
        for (int i = 0; i < 4; ++i)
            #pragma unroll
            for (int j = 0; j < 4; ++j)
                acc[i][j] = __builtin_amdgcn_mfma_f32_16x16x32_bf16(a[i], bf[j], acc[i][j], 0, 0, 0);
    }

    // epilogue: bias + scaled LeakyReLU (demod/factor already folded into wf)
    float bi[4][4];
    #pragma unroll
    for (int i = 0; i < 4; ++i)
        #pragma unroll
        for (int rr = 0; rr < 4; ++rr)
            bi[i][rr] = bias[o0 + mb + (i << 4) + (quad << 2) + rr];
    #pragma unroll
    for (int i = 0; i < 4; ++i) {
        #pragma unroll
        for (int j = 0; j < 4; ++j) {
            #pragma unroll
            for (int rr = 0; rr < 4; ++rr) {
                int oc = o0 + mb + (i << 4) + (quad << 2) + rr;
                int n = n0 + nb + (j << 4) + lr;
                int oh = n >> 6, ow2 = n & 63;
                float v = acc[i][j][rr] + bi[i][rr];
                v = (v >= 0.f ? v : 0.2f * v) * SQRT2;
                out[((bb + oc) << 12) + (oh << 6) + ow2] = v;
            }
        }
    }
}

extern "C" void kernel_launch(void* const* d_in, const int* in_sizes, int n_in,
                              void* d_out, int out_size, void* d_ws, size_t ws_size,
                              hipStream_t stream) {
    const float* x   = (const float*)d_in[0];
    const float* s   = (const float*)d_in[1];
    const float* cw  = (const float*)d_in[2];
    const float* cb  = (const float*)d_in[3];
    const float* sw  = (const float*)d_in[4];
    const float* sb  = (const float*)d_in[5];
    const float* ng  = (const float*)d_in[6];
    float* out = (float*)d_out;

    char* ws = (char*)d_ws;
    __hip_bfloat16* xblur = (__hip_bfloat16*)ws;                 // 67,108,864 B
    __hip_bfloat16* xbp   = (__hip_bfloat16*)(ws + 67108864);    // 69,222,400 B
    __hip_bfloat16* wfb   = (__hip_bfloat16*)(ws + 136331264);   //  9,437,184 B
    float* style  = (float*)(ws + 145768448);
    float* wsq    = style + 2048;
    float* demod  = wsq + 65536;
    float* ssq    = demod + 2048;
    float* factor = ssq + 2048;

    style_kernel<<<8, 256, 0, stream>>>(s, sw, sb, style);
    wsq_kernel<<<256, 256, 0, stream>>>(cw, wsq);
    demod_kernel<<<8, 256, 0, stream>>>(style, wsq, demod, ssq);
    blur_kernel<<<B * IC * 4, 256, 0, stream>>>(x, xblur, ssq);
    factor_kernel<<<8, 256, 0, stream>>>(ssq, style, ng, factor);
    wf_kernel<<<2048, 256, 0, stream>>>(cw, demod, factor, wfb);
    zeropad_kernel<<<32, 256, 0, stream>>>(xbp);
    pack_kernel<<<dim3(2, 4, 1024), 256, 0, stream>>>(xblur, xbp);
    conv_kernel<<<dim3(2, 32, 8), 256, 0, stream>>>(xbp, wfb, cb, out);
}